// Round 3
// baseline (1684.893 us; speedup 1.0000x reference)
//
#include <hip/hip_runtime.h>

typedef unsigned short u16;

// ---- problem constants ----
constexpr int NV = 50257;   // vocab
constexpr int ND = 512;     // hidden
constexpr int NT = 4096;    // seq len
constexpr int NB = 8;       // batch
constexpr int NM = NB * NT; // 32768 tokens
constexpr int NSLOTS = 256;
constexpr int NK = 8;       // lookahead window

__device__ __forceinline__ float b2f(u16 u) { return __uint_as_float(((unsigned)u) << 16); }
__device__ __forceinline__ u16 f2b(float f) {
    unsigned u = __float_as_uint(f);
    u += 0x7FFFu + ((u >> 16) & 1u);   // round-to-nearest-even
    return (u16)(u >> 16);
}

// Dual-dtype element loads. isf32 is wave-uniform (device-detected flag).
__device__ __forceinline__ float ld1(const void* p, size_t i, bool isf32) {
    return isf32 ? ((const float*)p)[i] : b2f(((const u16*)p)[i]);
}
__device__ __forceinline__ float4 ld4(const void* p, size_t i, bool isf32) {
    if (isf32) return *(const float4*)((const float*)p + i);
    ushort4 v = *(const ushort4*)((const u16*)p + i);
    return make_float4(b2f(v.x), b2f(v.y), b2f(v.z), b2f(v.w));
}

// ============================================================================
// Dtype detection: sample even-indexed u16s of W1 (512*1024 randn*0.02 elems).
// bf16 data -> exponent field in [100,130] for ~100% of samples.
// f32 data  -> even u16s are mantissa halves, exponent ~uniform -> ~12%.
// ============================================================================
__global__ __launch_bounds__(256) void k_detect(const void* w1, int* flag)
{
    __shared__ int red[256];
    const int tid = threadIdx.x;
    const u16* p = (const u16*)w1;
    int good = 0;
    for (int i = 0; i < 16; ++i) {
        u16 v = p[(size_t)(tid * 16 + i) * 2];   // even index
        int e = (v >> 7) & 0xFF;
        good += (e >= 100 && e <= 130) ? 1 : 0;
    }
    red[tid] = good;
    __syncthreads();
    for (int off = 128; off > 0; off >>= 1) {
        if (tid < off) red[tid] += red[tid + off];
        __syncthreads();
    }
    if (tid == 0) *flag = (red[0] < 2048) ? 1 : 0;   // <50% plausible => f32
}

// ============================================================================
// GEMM1 (chunked N): t1c[m][n] = relu( embed[seq[m]] @ W1[:, nOff+n] + b1 )
// M=32768, K=512. 128x128 tile, 256 thr, 8x8 microtile, KT=8.
// ============================================================================
__global__ __launch_bounds__(256) void k_gemm1(const void* __restrict__ embed,
                                               const int* __restrict__ seq,
                                               const void* __restrict__ W1,
                                               const void* __restrict__ b1,
                                               float* __restrict__ t1,
                                               int nOff, int ldT,
                                               const int* __restrict__ dflag)
{
    const bool isf32 = (*dflag != 0);
    __shared__ float As[8][128];
    __shared__ float Bs[8][128];
    __shared__ int   sSeq[128];
    const int tid = threadIdx.x;
    const int m0 = blockIdx.x * 128;
    const int n0 = blockIdx.y * 128;          // local (within chunk)
    const int ng = nOff + n0;                 // global column base
    if (tid < 128) sSeq[tid] = seq[m0 + tid];
    __syncthreads();
    const int tx = tid & 15, ty = tid >> 4;
    const int arow = tid >> 1, akk = (tid & 1) * 4;
    const int brow = tid >> 5, bcol = (tid & 31) * 4;
    const size_t abase = (size_t)sSeq[arow] * ND + akk;
    const size_t bbase = (size_t)brow * 1024 + ng + bcol;

    float acc[8][8];
#pragma unroll
    for (int i = 0; i < 8; ++i)
#pragma unroll
        for (int j = 0; j < 8; ++j) acc[i][j] = 0.f;

    for (int k0 = 0; k0 < 512; k0 += 8) {
        float4 av = ld4(embed, abase + k0, isf32);
        float4 bv = ld4(W1, bbase + (size_t)k0 * 1024, isf32);
        __syncthreads();
        As[akk + 0][arow] = av.x;
        As[akk + 1][arow] = av.y;
        As[akk + 2][arow] = av.z;
        As[akk + 3][arow] = av.w;
        Bs[brow][bcol + 0] = bv.x;
        Bs[brow][bcol + 1] = bv.y;
        Bs[brow][bcol + 2] = bv.z;
        Bs[brow][bcol + 3] = bv.w;
        __syncthreads();
#pragma unroll
        for (int kk = 0; kk < 8; ++kk) {
            float a[8], bb[8];
            *(float4*)(a)      = *(const float4*)&As[kk][ty * 4];
            *(float4*)(a + 4)  = *(const float4*)&As[kk][64 + ty * 4];
            *(float4*)(bb)     = *(const float4*)&Bs[kk][tx * 4];
            *(float4*)(bb + 4) = *(const float4*)&Bs[kk][64 + tx * 4];
#pragma unroll
            for (int i = 0; i < 8; ++i)
#pragma unroll
                for (int j = 0; j < 8; ++j) acc[i][j] += a[i] * bb[j];
        }
    }
    float bcv[8];
#pragma unroll
    for (int j = 0; j < 4; ++j) {
        bcv[j]     = ld1(b1, ng + tx * 4 + j, isf32);
        bcv[4 + j] = ld1(b1, ng + 64 + tx * 4 + j, isf32);
    }
#pragma unroll
    for (int ri = 0; ri < 8; ++ri) {
        int r = (ri < 4) ? (ty * 4 + ri) : (64 + ty * 4 + ri - 4);
        float* crow = t1 + (size_t)(m0 + r) * ldT + n0;
        float4 o;
        o.x = fmaxf(acc[ri][0] + bcv[0], 0.f);
        o.y = fmaxf(acc[ri][1] + bcv[1], 0.f);
        o.z = fmaxf(acc[ri][2] + bcv[2], 0.f);
        o.w = fmaxf(acc[ri][3] + bcv[3], 0.f);
        *(float4*)(crow + tx * 4) = o;
        o.x = fmaxf(acc[ri][4] + bcv[4], 0.f);
        o.y = fmaxf(acc[ri][5] + bcv[5], 0.f);
        o.z = fmaxf(acc[ri][6] + bcv[6], 0.f);
        o.w = fmaxf(acc[ri][7] + bcv[7], 0.f);
        *(float4*)(crow + 64 + tx * 4) = o;
    }
}

// ============================================================================
// GEMM2 (chunked K, accumulating): h[m][n] (+)= t1c[m] @ W2[kOff:kOff+kLen, n]
// pass 0 (init=1) adds b2[n] + embed[seq[m]][n]; later passes add to h.
// ============================================================================
__global__ __launch_bounds__(256) void k_gemm2(const float* __restrict__ t1,
                                               const void* __restrict__ W2,
                                               const void* __restrict__ b2v,
                                               const int* __restrict__ seq,
                                               const void* __restrict__ embed,
                                               float* __restrict__ h,
                                               int kOff, int kLen, int init,
                                               const int* __restrict__ dflag)
{
    const bool isf32 = (*dflag != 0);
    __shared__ float As[8][128];
    __shared__ float Bs[8][128];
    __shared__ int   sSeq[128];
    const int tid = threadIdx.x;
    const int m0 = blockIdx.x * 128;
    const int n0 = blockIdx.y * 128;
    if (tid < 128) sSeq[tid] = seq[m0 + tid];
    __syncthreads();
    const int tx = tid & 15, ty = tid >> 4;
    const int arow = tid >> 1, akk = (tid & 1) * 4;
    const int brow = tid >> 5, bcol = (tid & 31) * 4;
    const float* aptr = t1 + (size_t)(m0 + arow) * kLen + akk;
    const size_t bbase = (size_t)(kOff + brow) * 512 + n0 + bcol;

    float acc[8][8];
#pragma unroll
    for (int i = 0; i < 8; ++i)
#pragma unroll
        for (int j = 0; j < 8; ++j) acc[i][j] = 0.f;

    for (int k0 = 0; k0 < kLen; k0 += 8) {
        float4 av = *(const float4*)(aptr + k0);
        float4 bv = ld4(W2, bbase + (size_t)k0 * 512, isf32);
        __syncthreads();
        As[akk + 0][arow] = av.x;
        As[akk + 1][arow] = av.y;
        As[akk + 2][arow] = av.z;
        As[akk + 3][arow] = av.w;
        Bs[brow][bcol + 0] = bv.x;
        Bs[brow][bcol + 1] = bv.y;
        Bs[brow][bcol + 2] = bv.z;
        Bs[brow][bcol + 3] = bv.w;
        __syncthreads();
#pragma unroll
        for (int kk = 0; kk < 8; ++kk) {
            float a[8], bb[8];
            *(float4*)(a)      = *(const float4*)&As[kk][ty * 4];
            *(float4*)(a + 4)  = *(const float4*)&As[kk][64 + ty * 4];
            *(float4*)(bb)     = *(const float4*)&Bs[kk][tx * 4];
            *(float4*)(bb + 4) = *(const float4*)&Bs[kk][64 + tx * 4];
#pragma unroll
            for (int i = 0; i < 8; ++i)
#pragma unroll
                for (int j = 0; j < 8; ++j) acc[i][j] += a[i] * bb[j];
        }
    }
    float bcv[8];
#pragma unroll
    for (int j = 0; j < 4; ++j) {
        bcv[j]     = ld1(b2v, n0 + tx * 4 + j, isf32);
        bcv[4 + j] = ld1(b2v, n0 + 64 + tx * 4 + j, isf32);
    }
#pragma unroll
    for (int ri = 0; ri < 8; ++ri) {
        int r = (ri < 4) ? (ty * 4 + ri) : (64 + ty * 4 + ri - 4);
        float* crow = h + (size_t)(m0 + r) * ND + n0;
        float base0[8];
        if (init) {
            size_t ebase = (size_t)sSeq[r] * ND + n0;
            float4 e1 = ld4(embed, ebase + tx * 4, isf32);
            float4 e2 = ld4(embed, ebase + 64 + tx * 4, isf32);
            base0[0] = bcv[0] + e1.x;
            base0[1] = bcv[1] + e1.y;
            base0[2] = bcv[2] + e1.z;
            base0[3] = bcv[3] + e1.w;
            base0[4] = bcv[4] + e2.x;
            base0[5] = bcv[5] + e2.y;
            base0[6] = bcv[6] + e2.z;
            base0[7] = bcv[7] + e2.w;
        } else {
            float4 p1 = *(const float4*)(crow + tx * 4);
            float4 p2 = *(const float4*)(crow + 64 + tx * 4);
            base0[0] = p1.x; base0[1] = p1.y; base0[2] = p1.z; base0[3] = p1.w;
            base0[4] = p2.x; base0[5] = p2.y; base0[6] = p2.z; base0[7] = p2.w;
        }
        float4 o;
        o.x = acc[ri][0] + base0[0];
        o.y = acc[ri][1] + base0[1];
        o.z = acc[ri][2] + base0[2];
        o.w = acc[ri][3] + base0[3];
        *(float4*)(crow + tx * 4) = o;
        o.x = acc[ri][4] + base0[4];
        o.y = acc[ri][5] + base0[5];
        o.z = acc[ri][6] + base0[6];
        o.w = acc[ri][7] + base0[7];
        *(float4*)(crow + 64 + tx * 4) = o;
    }
}

// ============================================================================
// In-place LayerNorm over last dim (512), one block per row
// ============================================================================
__global__ __launch_bounds__(256) void k_ln(float* __restrict__ h,
                                            const void* __restrict__ g,
                                            const void* __restrict__ b,
                                            const int* __restrict__ dflag)
{
    const bool isf32 = (*dflag != 0);
    __shared__ float red[256];
    const int tid = threadIdx.x;
    float* p = h + (size_t)blockIdx.x * ND;
    float2 x = *(float2*)(p + tid * 2);
    red[tid] = x.x + x.y;
    __syncthreads();
    for (int off = 128; off > 0; off >>= 1) {
        if (tid < off) red[tid] += red[tid + off];
        __syncthreads();
    }
    float mean = red[0] * (1.f / 512.f);
    __syncthreads();
    float d0 = x.x - mean, d1 = x.y - mean;
    red[tid] = d0 * d0 + d1 * d1;
    __syncthreads();
    for (int off = 128; off > 0; off >>= 1) {
        if (tid < off) red[tid] += red[tid + off];
        __syncthreads();
    }
    float rstd = rsqrtf(red[0] * (1.f / 512.f) + 1e-5f);
    float2 o;
    o.x = d0 * rstd * ld1(g, tid * 2, isf32)     + ld1(b, tid * 2, isf32);
    o.y = d1 * rstd * ld1(g, tid * 2 + 1, isf32) + ld1(b, tid * 2 + 1, isf32);
    *(float2*)(p + tid * 2) = o;
}

// ============================================================================
// Per-token gate partial dots: g1[m]=h[m]·gW[0:512], g2[m]=h[m]·gW[512:1024]
// ============================================================================
__global__ __launch_bounds__(256) void k_g12(const float* __restrict__ h,
                                             const void* __restrict__ gW,
                                             float* __restrict__ g1,
                                             float* __restrict__ g2,
                                             const int* __restrict__ dflag)
{
    const bool isf32 = (*dflag != 0);
    const int lane = threadIdx.x & 63;
    const int m = blockIdx.x * 4 + (threadIdx.x >> 6);
    const float* row = h + (size_t)m * ND;
    const int d = lane * 8;
    float4 h0 = *(const float4*)(row + d);
    float4 h1 = *(const float4*)(row + d + 4);
    float4 wa = ld4(gW, d, isf32);
    float4 wb = ld4(gW, d + 4, isf32);
    float4 va = ld4(gW, 512 + d, isf32);
    float4 vb = ld4(gW, 512 + d + 4, isf32);
    float s1 = h0.x * wa.x + h0.y * wa.y + h0.z * wa.z + h0.w * wa.w
             + h1.x * wb.x + h1.y * wb.y + h1.z * wb.z + h1.w * wb.w;
    float s2 = h0.x * va.x + h0.y * va.y + h0.z * va.z + h0.w * va.w
             + h1.x * vb.x + h1.y * vb.y + h1.z * vb.z + h1.w * vb.w;
#pragma unroll
    for (int off = 32; off > 0; off >>= 1) {
        s1 += __shfl_down(s1, off, 64);
        s2 += __shfl_down(s2, off, 64);
    }
    if (lane == 0) { g1[m] = s1; g2[m] = s2; }
}

// ============================================================================
// Gate logit: g1[m] + mean(g2[m+1 .. m+cnt]), cnt = min(K, T-1-t)
// (sigmoid and gate_b dropped: monotone / constant => same top-k set)
// ============================================================================
__global__ __launch_bounds__(256) void k_gate(const float* __restrict__ g1,
                                              const float* __restrict__ g2,
                                              float* __restrict__ gate)
{
    int m = blockIdx.x * 256 + threadIdx.x;
    int t = m & (NT - 1);
    int cnt = min(NK, NT - 1 - t);
    float s = 0.f;
    for (int i = 1; i <= cnt; ++i) s += g2[m + i];
    float fut = (cnt > 0) ? s / (float)cnt : 0.f;
    gate[m] = g1[m] + fut;
}

// ============================================================================
// Exact top-256 of 4096 per batch via 32-round radix-select on sortable keys.
// Ties at threshold resolved by lowest index (matches jax.lax.top_k set).
// ============================================================================
__global__ __launch_bounds__(256) void k_topk(const float* __restrict__ gate,
                                              int* __restrict__ idxOut)
{
    __shared__ unsigned keys[NT];
    __shared__ int red[256];
    __shared__ int s_cnt;
    const int b = blockIdx.x, tid = threadIdx.x;
    const float* gr = gate + (size_t)b * NT;
    for (int i = tid; i < NT; i += 256) {
        unsigned u = __float_as_uint(gr[i]);
        u = (u & 0x80000000u) ? ~u : (u | 0x80000000u);
        keys[i] = u;
    }
    __syncthreads();
    unsigned sel = 0;
    for (int bit = 31; bit >= 0; --bit) {
        unsigned cand = sel | (1u << bit);
        int c = 0;
        for (int i = tid; i < NT; i += 256) c += (keys[i] >= cand) ? 1 : 0;
        red[tid] = c;
        __syncthreads();
        for (int off = 128; off > 0; off >>= 1) {
            if (tid < off) red[tid] += red[tid + off];
            __syncthreads();
        }
        int total = red[0];
        __syncthreads();
        if (total >= NSLOTS) sel = cand;
    }
    if (tid == 0) s_cnt = 0;
    __syncthreads();
    for (int i = tid; i < NT; i += 256) {
        if (keys[i] > sel) {
            int p = atomicAdd(&s_cnt, 1);
            idxOut[b * NSLOTS + p] = i;
        }
    }
    __syncthreads();
    if (tid == 0) {
        int p = s_cnt;
        for (int i = 0; i < NT && p < NSLOTS; ++i) {
            if (keys[i] == sel) { idxOut[b * NSLOTS + p] = i; ++p; }
        }
    }
}

// ============================================================================
// q[b] = h[b, T-1] @ q_W + q_b   (one block per batch)
// ============================================================================
__global__ __launch_bounds__(256) void k_q(const float* __restrict__ h,
                                           const void* __restrict__ qW,
                                           const void* __restrict__ qb,
                                           float* __restrict__ qo,
                                           const int* __restrict__ dflag)
{
    const bool isf32 = (*dflag != 0);
    const int b = blockIdx.x, tid = threadIdx.x;
    __shared__ float hl[ND];
    const float* row = h + ((size_t)b * NT + (NT - 1)) * ND;
    hl[tid] = row[tid];
    hl[256 + tid] = row[256 + tid];
    __syncthreads();
    for (int j = tid; j < ND; j += 256) {
        float acc = ld1(qb, j, isf32);
        for (int d = 0; d < ND; ++d) acc += hl[d] * ld1(qW, (size_t)d * ND + j, isf32);
        qo[b * ND + j] = acc;
    }
}

// ============================================================================
// scores -> softmax -> ctx  (one block per batch)
// ============================================================================
__global__ __launch_bounds__(256) void k_attn(const float* __restrict__ h,
                                              const float* __restrict__ q,
                                              const int* __restrict__ idx,
                                              float* __restrict__ ctx)
{
    const int b = blockIdx.x, tid = threadIdx.x;
    __shared__ float qv[ND];
    __shared__ float sc[256];
    __shared__ float red[256];
    __shared__ int sidx[256];
    qv[tid] = q[b * ND + tid];
    qv[256 + tid] = q[b * ND + 256 + tid];
    sidx[tid] = idx[b * NSLOTS + tid];
    __syncthreads();
    const float* hb = h + (size_t)b * NT * ND;
    {
        const float* row = hb + (size_t)sidx[tid] * ND;
        float s = 0.f;
        for (int d = 0; d < ND; d += 4) {
            float4 hv = *(const float4*)(row + d);
            float4 qq = *(const float4*)(qv + d);
            s += hv.x * qq.x + hv.y * qq.y + hv.z * qq.z + hv.w * qq.w;
        }
        sc[tid] = s;
        red[tid] = s;
    }
    __syncthreads();
    for (int off = 128; off > 0; off >>= 1) {
        if (tid < off) red[tid] = fmaxf(red[tid], red[tid + off]);
        __syncthreads();
    }
    float mx = red[0];
    __syncthreads();
    float e = expf(sc[tid] - mx);
    red[tid] = e;
    __syncthreads();
    for (int off = 128; off > 0; off >>= 1) {
        if (tid < off) red[tid] += red[tid + off];
        __syncthreads();
    }
    float inv = 1.f / red[0];
    __syncthreads();
    sc[tid] = e * inv;
    __syncthreads();
    for (int d = tid; d < ND; d += 256) {
        float acc = 0.f;
        for (int m = 0; m < NSLOTS; ++m) acc += sc[m] * hb[(size_t)sidx[m] * ND + d];
        ctx[b * ND + d] = acc;
    }
}

// ============================================================================
// out[b][v] = ctx[b] · out_W[:,v] + out_b[v]   (2 columns per thread)
// ============================================================================
__global__ __launch_bounds__(256) void k_out(const float* __restrict__ ctx,
                                             const void* __restrict__ outW,
                                             const void* __restrict__ outb,
                                             void* __restrict__ out,
                                             const int* __restrict__ dflag)
{
    const bool isf32 = (*dflag != 0);
    __shared__ float cs[NB * ND];
    const int tid = threadIdx.x;
    for (int i = tid; i < NB * ND; i += 256) cs[i] = ctx[i];
    __syncthreads();
    int v0 = blockIdx.x * 512 + tid * 2;
    if (v0 >= NV) return;
    bool two = (v0 + 1 < NV);
    float acc0[NB], acc1[NB];
#pragma unroll
    for (int bb = 0; bb < NB; ++bb) { acc0[bb] = 0.f; acc1[bb] = 0.f; }
    for (int d = 0; d < ND; ++d) {
        size_t wb = (size_t)d * NV + v0;
        float w0 = ld1(outW, wb, isf32);
        float w1 = two ? ld1(outW, wb + 1, isf32) : 0.f;
#pragma unroll
        for (int bb = 0; bb < NB; ++bb) {
            float c = cs[bb * ND + d];
            acc0[bb] += c * w0;
            acc1[bb] += c * w1;
        }
    }
    float ob0 = ld1(outb, v0, isf32);
    float ob1 = two ? ld1(outb, v0 + 1, isf32) : 0.f;
#pragma unroll
    for (int bb = 0; bb < NB; ++bb) {
        float r0 = acc0[bb] + ob0;
        float r1 = acc1[bb] + ob1;
        size_t o0 = (size_t)bb * NV + v0;
        if (isf32) {
            ((float*)out)[o0] = r0;
            if (two) ((float*)out)[o0 + 1] = r1;
        } else {
            ((u16*)out)[o0] = f2b(r0);
            if (two) ((u16*)out)[o0 + 1] = f2b(r1);
        }
    }
}

// ============================================================================
extern "C" void kernel_launch(void* const* d_in, const int* in_sizes, int n_in,
                              void* d_out, int out_size, void* d_ws, size_t ws_size,
                              hipStream_t stream)
{
    const int*  seq   = (const int*)d_in[0];
    const void* embed = d_in[1];
    const void* W1    = d_in[2];
    const void* b1    = d_in[3];
    const void* W2    = d_in[4];
    const void* b2v   = d_in[5];
    const void* lng   = d_in[6];
    const void* lnb   = d_in[7];
    const void* gateW = d_in[8];
    // d_in[9] = gate_b (constant shift, irrelevant for top-k ordering)
    const void* qW    = d_in[10];
    const void* qb    = d_in[11];
    const void* outW  = d_in[12];
    const void* outb  = d_in[13];

    // ---- ws layout: flag + small buffers first, then h (f32), then t1 chunk ----
    float* ws   = (float*)d_ws;
    int*   flag = (int*)ws;                    // ws[0..3] (16B pad)
    float* g1   = ws + 4;                      // NM
    float* g2   = g1 + NM;                     // NM
    float* gate = g2 + NM;                     // NM
    int*   idx  = (int*)(gate + NM);           // NB*NSLOTS
    float* qo   = (float*)(idx + NB * NSLOTS); // NB*ND
    float* ctx  = qo + NB * ND;                // NB*ND
    float* h    = ctx + NB * ND;               // NM*ND f32 (64 MiB)
    float* t1   = h + (size_t)NM * ND;         // NM*chunk f32

    // ws-adaptive chunk width for the FFN intermediate (t1 stays f32 for
    // top-k gate exactness). Branch depends only on ws_size: graph-safe.
    const size_t smallB = ((size_t)(4 + 3 * NM + NB * NSLOTS + 2 * NB * ND)) * 4;
    const size_t baseB  = smallB + (size_t)NM * ND * 4;
    int chunk;
    if      (ws_size >= baseB + (size_t)NM * 1024 * 4) chunk = 1024;
    else if (ws_size >= baseB + (size_t)NM * 256 * 4)  chunk = 256;
    else                                               chunk = 128;
    const int npass = 1024 / chunk;

    k_detect<<<1, 256, 0, stream>>>(W1, flag);
    for (int p = 0; p < npass; ++p) {
        k_gemm1<<<dim3(NM / 128, chunk / 128), 256, 0, stream>>>(
            embed, seq, W1, b1, t1, p * chunk, chunk, flag);
        k_gemm2<<<dim3(NM / 128, ND / 128), 256, 0, stream>>>(
            t1, W2, b2v, seq, embed, h, p * chunk, chunk, (p == 0) ? 1 : 0, flag);
    }
    k_ln<<<NM, 256, 0, stream>>>(h, lng, lnb, flag);
    k_g12<<<NM / 4, 256, 0, stream>>>(h, gateW, g1, g2, flag);
    k_gate<<<NM / 256, 256, 0, stream>>>(g1, g2, gate);
    k_topk<<<NB, 256, 0, stream>>>(gate, idx);
    k_q<<<NB, 256, 0, stream>>>(h, qW, qb, qo, flag);
    k_attn<<<NB, 256, 0, stream>>>(h, qo, idx, ctx);
    k_out<<<(NV + 511) / 512, 256, 0, stream>>>(ctx, outW, outb, d_out, flag);
}